// Round 1
// baseline (1157.048 us; speedup 1.0000x reference)
//
#include <hip/hip_runtime.h>
#include <hip/hip_bf16.h>

// ---------------------------------------------------------------------------
// SAGEConv: out = relu(concat(feature, segsum(feature[src], dst)/max(deg,1)) @ W + b)
// N=10000 nodes, E=160000 edges, D_IN=512, D_OUT=512, K=1024
// ---------------------------------------------------------------------------

#define N_NODES 10000
#define N_EDGES 160000
#define D_IN    512
#define D_OUT   512
#define K_DIM   1024

typedef float  f32x4  __attribute__((ext_vector_type(4)));
typedef __bf16 bf16x8 __attribute__((ext_vector_type(8)));
typedef unsigned short us8 __attribute__((ext_vector_type(8)));
typedef unsigned short us4 __attribute__((ext_vector_type(4)));

__device__ __forceinline__ unsigned short f2b(float f) {
    unsigned int u = __float_as_uint(f);
    unsigned int r = u + 0x7FFFu + ((u >> 16) & 1u);   // round-to-nearest-even
    return (unsigned short)(r >> 16);
}

// ---------------------------------------------------------------------------
// Kernel 1: W [1024][512] fp32  ->  WbT [512][1024] bf16 (transposed, n-major)
// LDS-tiled 32x32 transpose, coalesced both sides.
// ---------------------------------------------------------------------------
__global__ __launch_bounds__(256) void wtrans_kernel(const float* __restrict__ W,
                                                     unsigned short* __restrict__ WbT) {
    __shared__ float tile[32][33];
    const int kt = blockIdx.x;   // 0..31  (k tile)
    const int nt = blockIdx.y;   // 0..15  (n tile)
    const int t  = threadIdx.x;
    const int c  = t & 31;       // inner
    const int r0 = t >> 5;       // 0..7
#pragma unroll
    for (int p = 0; p < 4; ++p) {
        int r = r0 + p * 8;
        tile[r][c] = W[(size_t)(kt * 32 + r) * D_OUT + nt * 32 + c];
    }
    __syncthreads();
#pragma unroll
    for (int p = 0; p < 4; ++p) {
        int r = r0 + p * 8;       // local n
        // write WbT[n][k], consecutive c -> consecutive k (coalesced)
        WbT[(size_t)(nt * 32 + r) * K_DIM + kt * 32 + c] = f2b(tile[c][r]);
    }
}

// ---------------------------------------------------------------------------
// Kernel 2: edge scatter.  1 wave per edge.
//   neigh[dst] += feature[src]  (512 floats, atomic)
//   degs[dst]  += 1
// ---------------------------------------------------------------------------
__global__ __launch_bounds__(256) void scatter_kernel(const float* __restrict__ feat,
                                                      const int* __restrict__ src,
                                                      const int* __restrict__ dst,
                                                      float* __restrict__ neigh,
                                                      float* __restrict__ degs) {
    const int wave = threadIdx.x >> 6;
    const int lane = threadIdx.x & 63;
    const int e    = blockIdx.x * 4 + wave;   // grid sized exactly E/4
    const int s = src[e];
    const int d = dst[e];
    if (lane == 0) atomicAdd(&degs[d], 1.0f);
    const float4* f4 = (const float4*)(feat + (size_t)s * D_IN);
    float* nd = neigh + (size_t)d * D_IN;
#pragma unroll
    for (int it = 0; it < 2; ++it) {
        float4 v = f4[it * 64 + lane];
        int c = (it * 64 + lane) * 4;
        atomicAdd(nd + c + 0, v.x);
        atomicAdd(nd + c + 1, v.y);
        atomicAdd(nd + c + 2, v.z);
        atomicAdd(nd + c + 3, v.w);
    }
}

// ---------------------------------------------------------------------------
// Kernel 3: degs[i] = 1 / max(degs[i], 1)
// ---------------------------------------------------------------------------
__global__ __launch_bounds__(256) void invdeg_kernel(float* __restrict__ degs) {
    int i = blockIdx.x * 256 + threadIdx.x;
    if (i < N_NODES) degs[i] = 1.0f / fmaxf(degs[i], 1.0f);
}

// ---------------------------------------------------------------------------
// Kernel 4: GEMM  out[10000][512] = relu( X[10000][1024] @ Wb[1024][512] + b )
//   X[:, :512]  = feature (fp32 -> bf16 on the fly)
//   X[:, 512:]  = neigh * invdeg (fp32 -> bf16 on the fly)
// 128x128 tile, BK=32, 4 waves (2x2), 64x64 per wave, mfma_f32_16x16x32_bf16.
// LDS stride 40 bf16 (80 B, 16B-aligned rows, no serialising bank conflicts).
// ---------------------------------------------------------------------------
#define LDSTR 40

__global__ __launch_bounds__(256) void gemm_kernel(const float* __restrict__ feat,
                                                   const float* __restrict__ neigh,
                                                   const float* __restrict__ invdeg,
                                                   const unsigned short* __restrict__ WbT,
                                                   const float* __restrict__ bias,
                                                   float* __restrict__ out) {
    __shared__ __align__(16) unsigned short As[128 * LDSTR];
    __shared__ __align__(16) unsigned short Bs[128 * LDSTR];

    const int tid  = threadIdx.x;
    const int lane = tid & 63;
    const int w    = tid >> 6;
    const int wr   = w >> 1;        // 0..1
    const int wc   = w & 1;         // 0..1
    const int brow = blockIdx.x * 128;
    const int bcol = blockIdx.y * 128;

    f32x4 acc[4][4] = {};

    // A staging map: 8 threads/row * float4; 32 rows/pass, 4 passes
    const int ar0  = tid >> 3;          // 0..31
    const int acol = (tid & 7) * 4;     // 0,4,..,28
    // B staging map: 4 threads/row * 8 bf16; 64 rows/pass, 2 passes
    const int bn0  = tid >> 2;          // 0..63
    const int bk   = (tid & 3) * 8;     // 0,8,16,24

    for (int k0 = 0; k0 < K_DIM; k0 += 32) {
        const bool second = (k0 >= D_IN);
        const float* srcA = second ? (neigh + (k0 - D_IN)) : (feat + k0);

        // ---- stage A (fp32 -> bf16) ----
#pragma unroll
        for (int p = 0; p < 4; ++p) {
            int r  = ar0 + p * 32;
            int gr = brow + r;
            float4 v = make_float4(0.f, 0.f, 0.f, 0.f);
            if (gr < N_NODES) {
                v = *(const float4*)(srcA + (size_t)gr * D_IN + acol);
                if (second) {
                    float s = invdeg[gr];
                    v.x *= s; v.y *= s; v.z *= s; v.w *= s;
                }
            }
            us4 hv;
            hv.x = f2b(v.x); hv.y = f2b(v.y); hv.z = f2b(v.z); hv.w = f2b(v.w);
            *(us4*)(&As[r * LDSTR + acol]) = hv;
        }
        // ---- stage B (already bf16, Bt layout [n][k]) ----
#pragma unroll
        for (int p = 0; p < 2; ++p) {
            int n = bn0 + p * 64;
            *(us8*)(&Bs[n * LDSTR + bk]) =
                *(const us8*)(&WbT[(size_t)(bcol + n) * K_DIM + k0 + bk]);
        }
        __syncthreads();

        // ---- fragments + MFMA ----
        bf16x8 af[4], bfr[4];
#pragma unroll
        for (int m = 0; m < 4; ++m) {
            int r = wr * 64 + m * 16 + (lane & 15);
            af[m] = *(const bf16x8*)(&As[r * LDSTR + (lane >> 4) * 8]);
        }
#pragma unroll
        for (int n = 0; n < 4; ++n) {
            int c = wc * 64 + n * 16 + (lane & 15);
            bfr[n] = *(const bf16x8*)(&Bs[c * LDSTR + (lane >> 4) * 8]);
        }
#pragma unroll
        for (int m = 0; m < 4; ++m)
#pragma unroll
            for (int n = 0; n < 4; ++n)
                acc[m][n] = __builtin_amdgcn_mfma_f32_16x16x32_bf16(af[m], bfr[n], acc[m][n], 0, 0, 0);
        __syncthreads();
    }

    // ---- epilogue: bias + relu, fp32 out ----
#pragma unroll
    for (int n = 0; n < 4; ++n) {
        int col = bcol + wc * 64 + n * 16 + (lane & 15);
        float bv = bias[col];
#pragma unroll
        for (int m = 0; m < 4; ++m) {
            int row0 = brow + wr * 64 + m * 16 + (lane >> 4) * 4;
#pragma unroll
            for (int j = 0; j < 4; ++j) {
                int row = row0 + j;
                if (row < N_NODES) {
                    float v = acc[m][n][j] + bv;
                    out[(size_t)row * D_OUT + col] = fmaxf(v, 0.0f);
                }
            }
        }
    }
}

// ---------------------------------------------------------------------------
// Launch
// ws layout:
//   [0, 20480000)              neigh fp32 [10000][512]
//   [20480000, 20520000)       degs fp32 [10000]
//   [20520000, 21568576)       WbT bf16 [512][1024]
// ---------------------------------------------------------------------------
extern "C" void kernel_launch(void* const* d_in, const int* in_sizes, int n_in,
                              void* d_out, int out_size, void* d_ws, size_t ws_size,
                              hipStream_t stream) {
    const float* feat = (const float*)d_in[0];
    const int*   src  = (const int*)d_in[1];
    const int*   dst  = (const int*)d_in[2];
    const float* W    = (const float*)d_in[3];
    const float* bias = (const float*)d_in[4];
    float*       out  = (float*)d_out;

    char* ws = (char*)d_ws;
    float* neigh          = (float*)(ws);
    float* degs           = (float*)(ws + 20480000);
    unsigned short* WbT   = (unsigned short*)(ws + 20520000);

    // zero accumulators (re-done every call -> deterministic replays)
    hipMemsetAsync(neigh, 0, 20480000 + 40000, stream);

    wtrans_kernel<<<dim3(32, 16), 256, 0, stream>>>(W, WbT);
    scatter_kernel<<<N_EDGES / 4, 256, 0, stream>>>(feat, src, dst, neigh, degs);
    invdeg_kernel<<<(N_NODES + 255) / 256, 256, 0, stream>>>(degs);
    gemm_kernel<<<dim3(79, 4), 256, 0, stream>>>(feat, neigh, degs, WbT, bias, out);
}

// Round 2
// 178.001 us; speedup vs baseline: 6.5002x; 6.5002x over previous
//
#include <hip/hip_runtime.h>
#include <hip/hip_bf16.h>

// ---------------------------------------------------------------------------
// SAGEConv: out = relu(concat(feature, mean_{src->dst}(feature)) @ W + b)
// N=10000 nodes, E=160000 edges, D_IN=512, D_OUT=512, K=1024
// Round 2: atomic scatter (1071us) -> CSR build + atomic-free gather.
// ---------------------------------------------------------------------------

#define N_NODES 10000
#define N_EDGES 160000
#define D_IN    512
#define D_OUT   512
#define K_DIM   1024

typedef float  f32x4  __attribute__((ext_vector_type(4)));
typedef __bf16 bf16x8 __attribute__((ext_vector_type(8)));
typedef unsigned short us8 __attribute__((ext_vector_type(8)));
typedef unsigned short us4 __attribute__((ext_vector_type(4)));

__device__ __forceinline__ unsigned short f2b(float f) {
    unsigned int u = __float_as_uint(f);
    unsigned int r = u + 0x7FFFu + ((u >> 16) & 1u);   // round-to-nearest-even
    return (unsigned short)(r >> 16);
}

// ---------------------------------------------------------------------------
// Kernel 1: W [1024][512] fp32 -> WbT [512][1024] bf16 (transposed)
// ---------------------------------------------------------------------------
__global__ __launch_bounds__(256) void wtrans_kernel(const float* __restrict__ W,
                                                     unsigned short* __restrict__ WbT) {
    __shared__ float tile[32][33];
    const int kt = blockIdx.x;   // 0..31
    const int nt = blockIdx.y;   // 0..15
    const int t  = threadIdx.x;
    const int c  = t & 31;
    const int r0 = t >> 5;
#pragma unroll
    for (int p = 0; p < 4; ++p) {
        int r = r0 + p * 8;
        tile[r][c] = W[(size_t)(kt * 32 + r) * D_OUT + nt * 32 + c];
    }
    __syncthreads();
#pragma unroll
    for (int p = 0; p < 4; ++p) {
        int r = r0 + p * 8;
        WbT[(size_t)(nt * 32 + r) * K_DIM + kt * 32 + c] = f2b(tile[c][r]);
    }
}

// ---------------------------------------------------------------------------
// Kernel 2: histogram of dst -> cnt
// ---------------------------------------------------------------------------
__global__ __launch_bounds__(256) void hist_kernel(const int* __restrict__ dst,
                                                   int* __restrict__ cnt) {
    int e = blockIdx.x * 256 + threadIdx.x;   // grid sized exactly E/256
    atomicAdd(&cnt[dst[e]], 1);
}

// ---------------------------------------------------------------------------
// Kernel 3: exclusive scan of cnt[10000] -> rowstart[10001], cursor = rowstart
// Single block, 256 threads, 40 elements/thread.
// ---------------------------------------------------------------------------
__global__ __launch_bounds__(256) void scan_kernel(const int* __restrict__ cnt,
                                                   int* __restrict__ rowstart,
                                                   int* __restrict__ cursor) {
    __shared__ int sums[256];
    const int t = threadIdx.x;
    const int base = t * 40;
    int s = 0;
#pragma unroll 8
    for (int i = 0; i < 40; ++i) {
        int idx = base + i;
        s += (idx < N_NODES) ? cnt[idx] : 0;
    }
    sums[t] = s;
    __syncthreads();
    for (int off = 1; off < 256; off <<= 1) {
        int v = (t >= off) ? sums[t - off] : 0;
        __syncthreads();
        sums[t] += v;
        __syncthreads();
    }
    int run = (t == 0) ? 0 : sums[t - 1];
    for (int i = 0; i < 40; ++i) {
        int idx = base + i;
        if (idx < N_NODES) {
            rowstart[idx] = run;
            cursor[idx]   = run;
            run += cnt[idx];
        }
    }
    if (t == 255) rowstart[N_NODES] = sums[255];
}

// ---------------------------------------------------------------------------
// Kernel 4: bucket fill.  eidx[cursor[d]++] = src[e]
// ---------------------------------------------------------------------------
__global__ __launch_bounds__(256) void bucket_kernel(const int* __restrict__ src,
                                                     const int* __restrict__ dst,
                                                     int* __restrict__ cursor,
                                                     int* __restrict__ eidx) {
    int e = blockIdx.x * 256 + threadIdx.x;
    int d = dst[e];
    int slot = atomicAdd(&cursor[d], 1);
    eidx[slot] = src[e];
}

// ---------------------------------------------------------------------------
// Kernel 5: gather-mean.  One block per node; thread t owns cols [2t, 2t+1].
//   neigh[node] = (1/max(deg,1)) * sum_j feature[eidx[j]]
// ---------------------------------------------------------------------------
__global__ __launch_bounds__(256) void gather_kernel(const float* __restrict__ feat,
                                                     const int* __restrict__ eidx,
                                                     const int* __restrict__ rowstart,
                                                     float* __restrict__ neigh) {
    const int node = blockIdx.x;
    const int t    = threadIdx.x;
    const int beg  = rowstart[node];
    const int end  = rowstart[node + 1];
    float ax = 0.f, ay = 0.f;
    for (int j = beg; j < end; ++j) {
        int s = eidx[j];                               // wave-uniform broadcast
        float2 v = *(const float2*)(feat + (size_t)s * D_IN + t * 2);
        ax += v.x; ay += v.y;
    }
    float scale = 1.0f / fmaxf((float)(end - beg), 1.0f);
    float2 r; r.x = ax * scale; r.y = ay * scale;
    *(float2*)(neigh + (size_t)node * D_IN + t * 2) = r;
}

// ---------------------------------------------------------------------------
// Kernel 6: GEMM  out[10000][512] = relu( X[10000][1024] @ Wb[1024][512] + b )
//   X[:, :512] = feature, X[:, 512:] = neigh (already mean-scaled), fp32->bf16.
// 128x128 tile, BK=32, 4 waves (2x2), 64x64/wave, mfma_f32_16x16x32_bf16.
// ---------------------------------------------------------------------------
#define LDSTR 40

__global__ __launch_bounds__(256) void gemm_kernel(const float* __restrict__ feat,
                                                   const float* __restrict__ neigh,
                                                   const unsigned short* __restrict__ WbT,
                                                   const float* __restrict__ bias,
                                                   float* __restrict__ out) {
    __shared__ __align__(16) unsigned short As[128 * LDSTR];
    __shared__ __align__(16) unsigned short Bs[128 * LDSTR];

    const int tid  = threadIdx.x;
    const int lane = tid & 63;
    const int w    = tid >> 6;
    const int wr   = w >> 1;
    const int wc   = w & 1;
    const int brow = blockIdx.x * 128;
    const int bcol = blockIdx.y * 128;

    f32x4 acc[4][4] = {};

    const int ar0  = tid >> 3;          // 0..31
    const int acol = (tid & 7) * 4;     // 0..28
    const int bn0  = tid >> 2;          // 0..63
    const int bk   = (tid & 3) * 8;     // 0..24

    for (int k0 = 0; k0 < K_DIM; k0 += 32) {
        const float* srcA = (k0 >= D_IN) ? (neigh + (k0 - D_IN)) : (feat + k0);

#pragma unroll
        for (int p = 0; p < 4; ++p) {
            int r  = ar0 + p * 32;
            int gr = brow + r;
            float4 v = make_float4(0.f, 0.f, 0.f, 0.f);
            if (gr < N_NODES) v = *(const float4*)(srcA + (size_t)gr * D_IN + acol);
            us4 hv;
            hv.x = f2b(v.x); hv.y = f2b(v.y); hv.z = f2b(v.z); hv.w = f2b(v.w);
            *(us4*)(&As[r * LDSTR + acol]) = hv;
        }
#pragma unroll
        for (int p = 0; p < 2; ++p) {
            int n = bn0 + p * 64;
            *(us8*)(&Bs[n * LDSTR + bk]) =
                *(const us8*)(&WbT[(size_t)(bcol + n) * K_DIM + k0 + bk]);
        }
        __syncthreads();

        bf16x8 af[4], bfr[4];
#pragma unroll
        for (int m = 0; m < 4; ++m) {
            int r = wr * 64 + m * 16 + (lane & 15);
            af[m] = *(const bf16x8*)(&As[r * LDSTR + (lane >> 4) * 8]);
        }
#pragma unroll
        for (int n = 0; n < 4; ++n) {
            int c = wc * 64 + n * 16 + (lane & 15);
            bfr[n] = *(const bf16x8*)(&Bs[c * LDSTR + (lane >> 4) * 8]);
        }
#pragma unroll
        for (int m = 0; m < 4; ++m)
#pragma unroll
            for (int n = 0; n < 4; ++n)
                acc[m][n] = __builtin_amdgcn_mfma_f32_16x16x32_bf16(af[m], bfr[n], acc[m][n], 0, 0, 0);
        __syncthreads();
    }

#pragma unroll
    for (int n = 0; n < 4; ++n) {
        int col = bcol + wc * 64 + n * 16 + (lane & 15);
        float bv = bias[col];
#pragma unroll
        for (int m = 0; m < 4; ++m) {
            int row0 = brow + wr * 64 + m * 16 + (lane >> 4) * 4;
#pragma unroll
            for (int j = 0; j < 4; ++j) {
                int row = row0 + j;
                if (row < N_NODES) {
                    float v = acc[m][n][j] + bv;
                    out[(size_t)row * D_OUT + col] = fmaxf(v, 0.0f);
                }
            }
        }
    }
}

// ---------------------------------------------------------------------------
// Launch.  ws layout (bytes):
//   [0,          20480000)  neigh     fp32 [10000][512]
//   [20480000,   20520000)  cnt       int  [10000]
//   [20520000,   20560016)  rowstart  int  [10001] (padded)
//   [20560016,   20600032)  cursor    int  [10001] (padded)
//   [20600032,   21240032)  eidx      int  [160000]
//   [21240032,   22288608)  WbT       bf16 [512][1024]
// ---------------------------------------------------------------------------
extern "C" void kernel_launch(void* const* d_in, const int* in_sizes, int n_in,
                              void* d_out, int out_size, void* d_ws, size_t ws_size,
                              hipStream_t stream) {
    const float* feat = (const float*)d_in[0];
    const int*   src  = (const int*)d_in[1];
    const int*   dst  = (const int*)d_in[2];
    const float* W    = (const float*)d_in[3];
    const float* bias = (const float*)d_in[4];
    float*       out  = (float*)d_out;

    char* ws = (char*)d_ws;
    float* neigh        = (float*)(ws);
    int*   cnt          = (int*)(ws + 20480000);
    int*   rowstart     = (int*)(ws + 20520000);
    int*   cursor       = (int*)(ws + 20560016);
    int*   eidx         = (int*)(ws + 20600032);
    unsigned short* WbT = (unsigned short*)(ws + 21240032);

    // zero the histogram (re-done every call -> deterministic replays)
    hipMemsetAsync(cnt, 0, 40000, stream);

    wtrans_kernel<<<dim3(32, 16), 256, 0, stream>>>(W, WbT);
    hist_kernel<<<N_EDGES / 256, 256, 0, stream>>>(dst, cnt);
    scan_kernel<<<1, 256, 0, stream>>>(cnt, rowstart, cursor);
    bucket_kernel<<<N_EDGES / 256, 256, 0, stream>>>(src, dst, cursor, eidx);
    gather_kernel<<<N_NODES, 256, 0, stream>>>(feat, eidx, rowstart, neigh);
    gemm_kernel<<<dim3(79, 4), 256, 0, stream>>>(feat, neigh, WbT, bias, out);
}

// Round 3
// 120.704 us; speedup vs baseline: 9.5858x; 1.4747x over previous
//
#include <hip/hip_runtime.h>
#include <hip/hip_bf16.h>

// ---------------------------------------------------------------------------
// SAGEConv: out = relu(concat(feature, mean_{src->dst}(feature)) @ W + b)
// N=10000 nodes, E=160000 edges, D_IN=512, D_OUT=512, K=1024
// Round 3: bf16 X materialization + gload_lds double-buffered 64x64 GEMM.
// ---------------------------------------------------------------------------

#define N_NODES 10000
#define N_EDGES 160000
#define D_IN    512
#define D_OUT   512
#define K_DIM   1024

typedef float  f32x4  __attribute__((ext_vector_type(4)));
typedef __bf16 bf16x8 __attribute__((ext_vector_type(8)));
typedef unsigned short us8 __attribute__((ext_vector_type(8)));

__device__ __forceinline__ unsigned short f2b(float f) {
    unsigned int u = __float_as_uint(f);
    unsigned int r = u + 0x7FFFu + ((u >> 16) & 1u);   // round-to-nearest-even
    return (unsigned short)(r >> 16);
}
__device__ __forceinline__ float b2f(unsigned short h) {
    return __uint_as_float(((unsigned int)h) << 16);
}
// global -> LDS direct 16B load. LDS dest must be wave-uniform base
// (HW writes lane l at base + l*16); global src is per-lane.
__device__ __forceinline__ void gl_lds16(const void* g, void* l) {
    auto gp = (const __attribute__((address_space(1))) unsigned int*)(uintptr_t)g;
    auto lp = (__attribute__((address_space(3))) unsigned int*)(uintptr_t)l;
    __builtin_amdgcn_global_load_lds(gp, lp, 16, 0, 0);
}

// ---------------------------------------------------------------------------
// Kernel 1: feat fp32 -> Xb[:, :512] bf16, fused dst-histogram.
// 2500 blocks x 256; thread owns 8 cols of one row.
// ---------------------------------------------------------------------------
__global__ __launch_bounds__(256) void convert_hist_kernel(const float* __restrict__ feat,
                                                           const int* __restrict__ dst,
                                                           unsigned short* __restrict__ Xb,
                                                           int* __restrict__ cnt) {
    const int gid = blockIdx.x * 256 + threadIdx.x;
    const int row = gid >> 6;
    const int l   = gid & 63;
    const float4* s = (const float4*)(feat + (size_t)row * D_IN + l * 8);
    float4 v0 = s[0], v1 = s[1];
    us8 o;
    o[0] = f2b(v0.x); o[1] = f2b(v0.y); o[2] = f2b(v0.z); o[3] = f2b(v0.w);
    o[4] = f2b(v1.x); o[5] = f2b(v1.y); o[6] = f2b(v1.z); o[7] = f2b(v1.w);
    *(us8*)(Xb + (size_t)row * K_DIM + l * 8) = o;
    if (gid < N_EDGES) atomicAdd(&cnt[dst[gid]], 1);
}

// ---------------------------------------------------------------------------
// Kernel 2: W [1024][512] fp32 -> WbT [512][1024] bf16 (transposed)
// ---------------------------------------------------------------------------
__global__ __launch_bounds__(256) void wtrans_kernel(const float* __restrict__ W,
                                                     unsigned short* __restrict__ WbT) {
    __shared__ float tile[32][33];
    const int kt = blockIdx.x;   // 0..31
    const int nt = blockIdx.y;   // 0..15
    const int t  = threadIdx.x;
    const int c  = t & 31;
    const int r0 = t >> 5;
#pragma unroll
    for (int p = 0; p < 4; ++p) {
        int r = r0 + p * 8;
        tile[r][c] = W[(size_t)(kt * 32 + r) * D_OUT + nt * 32 + c];
    }
    __syncthreads();
#pragma unroll
    for (int p = 0; p < 4; ++p) {
        int r = r0 + p * 8;
        WbT[(size_t)(nt * 32 + r) * K_DIM + kt * 32 + c] = f2b(tile[c][r]);
    }
}

// ---------------------------------------------------------------------------
// Kernel 3: exclusive scan cnt[10000] -> rowstart[10001], cursor = rowstart
// ---------------------------------------------------------------------------
__global__ __launch_bounds__(256) void scan_kernel(const int* __restrict__ cnt,
                                                   int* __restrict__ rowstart,
                                                   int* __restrict__ cursor) {
    __shared__ int sums[256];
    const int t = threadIdx.x;
    const int base = t * 40;
    int s = 0;
#pragma unroll 8
    for (int i = 0; i < 40; ++i) {
        int idx = base + i;
        s += (idx < N_NODES) ? cnt[idx] : 0;
    }
    sums[t] = s;
    __syncthreads();
    for (int off = 1; off < 256; off <<= 1) {
        int v = (t >= off) ? sums[t - off] : 0;
        __syncthreads();
        sums[t] += v;
        __syncthreads();
    }
    int run = (t == 0) ? 0 : sums[t - 1];
    for (int i = 0; i < 40; ++i) {
        int idx = base + i;
        if (idx < N_NODES) {
            rowstart[idx] = run;
            cursor[idx]   = run;
            run += cnt[idx];
        }
    }
    if (t == 255) rowstart[N_NODES] = sums[255];
}

// ---------------------------------------------------------------------------
// Kernel 4: bucket fill.  eidx[cursor[d]++] = src[e]
// ---------------------------------------------------------------------------
__global__ __launch_bounds__(256) void bucket_kernel(const int* __restrict__ src,
                                                     const int* __restrict__ dst,
                                                     int* __restrict__ cursor,
                                                     int* __restrict__ eidx) {
    int e = blockIdx.x * 256 + threadIdx.x;
    int d = dst[e];
    int slot = atomicAdd(&cursor[d], 1);
    eidx[slot] = src[e];
}

// ---------------------------------------------------------------------------
// Kernel 5: gather-mean (bf16 in, bf16 out).  One wave per node.
//   Xb[node][512:1024] = (1/max(deg,1)) * sum_j Xb[eidx[j]][0:512]
// ---------------------------------------------------------------------------
__global__ __launch_bounds__(256) void gather_kernel(unsigned short* Xb,
                                                     const int* __restrict__ eidx,
                                                     const int* __restrict__ rowstart) {
    const int wv   = threadIdx.x >> 6;
    const int l    = threadIdx.x & 63;
    const int node = blockIdx.x * 4 + wv;
    const int beg  = rowstart[node];
    const int end  = rowstart[node + 1];
    float acc[8] = {0.f, 0.f, 0.f, 0.f, 0.f, 0.f, 0.f, 0.f};
    int j = beg;
    for (; j + 2 <= end; j += 2) {
        int s0 = eidx[j], s1 = eidx[j + 1];
        us8 v0 = *(const us8*)(Xb + (size_t)s0 * K_DIM + l * 8);
        us8 v1 = *(const us8*)(Xb + (size_t)s1 * K_DIM + l * 8);
#pragma unroll
        for (int i = 0; i < 8; ++i) { acc[i] += b2f(v0[i]); acc[i] += b2f(v1[i]); }
    }
    if (j < end) {
        int s0 = eidx[j];
        us8 v0 = *(const us8*)(Xb + (size_t)s0 * K_DIM + l * 8);
#pragma unroll
        for (int i = 0; i < 8; ++i) acc[i] += b2f(v0[i]);
    }
    float sc = 1.0f / fmaxf((float)(end - beg), 1.0f);
    us8 o;
#pragma unroll
    for (int i = 0; i < 8; ++i) o[i] = f2b(acc[i] * sc);
    *(us8*)(Xb + (size_t)node * K_DIM + D_IN + l * 8) = o;
}

// ---------------------------------------------------------------------------
// Kernel 6: GEMM  out[10000][512] = relu( Xb[10000][1024] @ WbT^T + b )
// 64x64 tile, BK=64, 4 waves (2x2), 32x32/wave, mfma_f32_16x16x32_bf16.
// Double-buffered LDS via global_load_lds(16B); XOR-swizzle (row&7)<<4 applied
// to the global SOURCE address (linear LDS dest) and to the ds_read address.
// ---------------------------------------------------------------------------
__global__ __launch_bounds__(256, 5) void gemm_kernel(const unsigned short* __restrict__ Xb,
                                                      const unsigned short* __restrict__ WbT,
                                                      const float* __restrict__ bias,
                                                      float* __restrict__ out) {
    __shared__ __align__(16) unsigned short As[2][4096];   // [64 rows][64 k] bf16
    __shared__ __align__(16) unsigned short Bs[2][4096];   // [64 cols][64 k] bf16

    const int tid = threadIdx.x;
    const int l   = tid & 63;
    const int w   = tid >> 6;
    const int wr  = w >> 1, wc = w & 1;
    const int brow = blockIdx.x * 64;
    const int bcol = blockIdx.y * 64;

    // ---- staging source pointers (inverse-swizzled global addresses) ----
    // wave w, pass p covers LDS rows p*32 + w*8 .. +7; lane l -> row sub = l>>3,
    // 16B chunk (l&7). row&7 == l>>3 for all passes.
    const int sub  = l >> 3;
    const int scol = ((l & 7) * 16) ^ (sub * 16);
    int ra0 = brow + w * 8 + sub;      ra0 = ra0 < N_NODES ? ra0 : N_NODES - 1;
    int ra1 = brow + 32 + w * 8 + sub; ra1 = ra1 < N_NODES ? ra1 : N_NODES - 1;
    const char* pa0 = (const char*)Xb  + (size_t)ra0 * 2048 + scol;
    const char* pa1 = (const char*)Xb  + (size_t)ra1 * 2048 + scol;
    const char* pb0 = (const char*)WbT + (size_t)(bcol + w * 8 + sub) * 2048 + scol;
    const char* pb1 = pb0 + 32 * 2048;

#define STAGE(buf, koff) do {                              \
        gl_lds16(pa0 + (koff), &As[buf][w * 512]);         \
        gl_lds16(pa1 + (koff), &As[buf][2048 + w * 512]);  \
        gl_lds16(pb0 + (koff), &Bs[buf][w * 512]);         \
        gl_lds16(pb1 + (koff), &Bs[buf][2048 + w * 512]);  \
    } while (0)

    // ---- fragment read addresses (swizzled) ----
    const int fr = l & 15;
    const int g  = l >> 4;
    const int sw = (fr & 7) * 16;                 // row&7 == fr&7
    const int h0 = (((g * 16)      ) ^ sw) >> 1;  // k-half 0, shorts
    const int h1 = (((64 + g * 16) ) ^ sw) >> 1;  // k-half 1
    const int rA = (wr * 32 + fr) * 64;
    const int rB = (wc * 32 + fr) * 64;

    f32x4 acc[2][2] = {};

    STAGE(0, 0);
    __syncthreads();
    int cur = 0;
#pragma unroll
    for (int t = 0; t < 16; ++t) {
        if (t < 15) STAGE(cur ^ 1, (t + 1) * 128);
        bf16x8 a00 = *(const bf16x8*)&As[cur][rA + h0];
        bf16x8 a01 = *(const bf16x8*)&As[cur][rA + h1];
        bf16x8 a10 = *(const bf16x8*)&As[cur][rA + 1024 + h0];
        bf16x8 a11 = *(const bf16x8*)&As[cur][rA + 1024 + h1];
        bf16x8 b00 = *(const bf16x8*)&Bs[cur][rB + h0];
        bf16x8 b01 = *(const bf16x8*)&Bs[cur][rB + h1];
        bf16x8 b10 = *(const bf16x8*)&Bs[cur][rB + 1024 + h0];
        bf16x8 b11 = *(const bf16x8*)&Bs[cur][rB + 1024 + h1];
        acc[0][0] = __builtin_amdgcn_mfma_f32_16x16x32_bf16(a00, b00, acc[0][0], 0, 0, 0);
        acc[0][0] = __builtin_amdgcn_mfma_f32_16x16x32_bf16(a01, b01, acc[0][0], 0, 0, 0);
        acc[0][1] = __builtin_amdgcn_mfma_f32_16x16x32_bf16(a00, b10, acc[0][1], 0, 0, 0);
        acc[0][1] = __builtin_amdgcn_mfma_f32_16x16x32_bf16(a01, b11, acc[0][1], 0, 0, 0);
        acc[1][0] = __builtin_amdgcn_mfma_f32_16x16x32_bf16(a10, b00, acc[1][0], 0, 0, 0);
        acc[1][0] = __builtin_amdgcn_mfma_f32_16x16x32_bf16(a11, b01, acc[1][0], 0, 0, 0);
        acc[1][1] = __builtin_amdgcn_mfma_f32_16x16x32_bf16(a10, b10, acc[1][1], 0, 0, 0);
        acc[1][1] = __builtin_amdgcn_mfma_f32_16x16x32_bf16(a11, b11, acc[1][1], 0, 0, 0);
        __syncthreads();
        cur ^= 1;
    }
#undef STAGE

    // ---- epilogue: bias + relu ----
#pragma unroll
    for (int n = 0; n < 2; ++n) {
        int col = bcol + wc * 32 + n * 16 + fr;
        float bv = bias[col];
#pragma unroll
        for (int m = 0; m < 2; ++m) {
            int row0 = brow + wr * 32 + m * 16 + g * 4;
#pragma unroll
            for (int j = 0; j < 4; ++j) {
                int row = row0 + j;
                if (row < N_NODES)
                    out[(size_t)row * D_OUT + col] = fmaxf(acc[m][n][j] + bv, 0.0f);
            }
        }
    }
}

// ---------------------------------------------------------------------------
// Launch.  ws layout (bytes):
//   [0,          20480000)  Xb        bf16 [10000][1024] (left=feat, right=mean)
//   [20480000,   20520000)  cnt       int  [10000]
//   [20520000,   20560016)  rowstart  int  [10001] (padded)
//   [20560016,   20600032)  cursor    int  [10001] (padded)
//   [20600032,   21240032)  eidx      int  [160000]
//   [21240032,   22288608)  WbT       bf16 [512][1024]
// ---------------------------------------------------------------------------
extern "C" void kernel_launch(void* const* d_in, const int* in_sizes, int n_in,
                              void* d_out, int out_size, void* d_ws, size_t ws_size,
                              hipStream_t stream) {
    const float* feat = (const float*)d_in[0];
    const int*   src  = (const int*)d_in[1];
    const int*   dst  = (const int*)d_in[2];
    const float* W    = (const float*)d_in[3];
    const float* bias = (const float*)d_in[4];
    float*       out  = (float*)d_out;

    char* ws = (char*)d_ws;
    unsigned short* Xb  = (unsigned short*)(ws);
    int*   cnt          = (int*)(ws + 20480000);
    int*   rowstart     = (int*)(ws + 20520000);
    int*   cursor       = (int*)(ws + 20560016);
    int*   eidx         = (int*)(ws + 20600032);
    unsigned short* WbT = (unsigned short*)(ws + 21240032);

    hipMemsetAsync(cnt, 0, 40000, stream);
    convert_hist_kernel<<<2500, 256, 0, stream>>>(feat, dst, Xb, cnt);
    wtrans_kernel<<<dim3(32, 16), 256, 0, stream>>>(W, WbT);
    scan_kernel<<<1, 256, 0, stream>>>(cnt, rowstart, cursor);
    bucket_kernel<<<N_EDGES / 256, 256, 0, stream>>>(src, dst, cursor, eidx);
    gather_kernel<<<2500, 256, 0, stream>>>(Xb, eidx, rowstart);
    gemm_kernel<<<dim3(157, 8), 256, 0, stream>>>(Xb, WbT, bias, out);
}

// Round 4
// 118.395 us; speedup vs baseline: 9.7728x; 1.0195x over previous
//
#include <hip/hip_runtime.h>
#include <hip/hip_bf16.h>

// ---------------------------------------------------------------------------
// SAGEConv: out = relu(concat(feature, mean_{src->dst}(feature)) @ W + b)
// N=10000 nodes, E=160000 edges, D_IN=512, D_OUT=512, K=1024
// Round 4: drop hipMemsetAsync (rocclr fill = 42us for 40KB!); zero cnt inside
// wtrans_kernel, which now runs first in the stream.
// ---------------------------------------------------------------------------

#define N_NODES 10000
#define N_EDGES 160000
#define D_IN    512
#define D_OUT   512
#define K_DIM   1024

typedef float  f32x4  __attribute__((ext_vector_type(4)));
typedef __bf16 bf16x8 __attribute__((ext_vector_type(8)));
typedef unsigned short us8 __attribute__((ext_vector_type(8)));

__device__ __forceinline__ unsigned short f2b(float f) {
    unsigned int u = __float_as_uint(f);
    unsigned int r = u + 0x7FFFu + ((u >> 16) & 1u);   // round-to-nearest-even
    return (unsigned short)(r >> 16);
}
__device__ __forceinline__ float b2f(unsigned short h) {
    return __uint_as_float(((unsigned int)h) << 16);
}
// global -> LDS direct 16B load. LDS dest is wave-uniform base + lane*16;
// global src is per-lane.
__device__ __forceinline__ void gl_lds16(const void* g, void* l) {
    auto gp = (const __attribute__((address_space(1))) unsigned int*)(uintptr_t)g;
    auto lp = (__attribute__((address_space(3))) unsigned int*)(uintptr_t)l;
    __builtin_amdgcn_global_load_lds(gp, lp, 16, 0, 0);
}

// ---------------------------------------------------------------------------
// Kernel 1 (runs FIRST): W [1024][512] fp32 -> WbT [512][1024] bf16,
// fused cnt-zeroing (512 blocks x 20 ints = 10240 >= 10000).
// ---------------------------------------------------------------------------
__global__ __launch_bounds__(256) void wtrans_kernel(const float* __restrict__ W,
                                                     unsigned short* __restrict__ WbT,
                                                     int* __restrict__ cnt) {
    const int kt = blockIdx.x;   // 0..31
    const int nt = blockIdx.y;   // 0..15
    const int t  = threadIdx.x;

    // zero the histogram slice owned by this block
    const int bid = nt * 32 + kt;
    const int zi  = bid * 20 + t;
    if (t < 20 && zi < N_NODES) cnt[zi] = 0;

    __shared__ float tile[32][33];
    const int c  = t & 31;
    const int r0 = t >> 5;
#pragma unroll
    for (int p = 0; p < 4; ++p) {
        int r = r0 + p * 8;
        tile[r][c] = W[(size_t)(kt * 32 + r) * D_OUT + nt * 32 + c];
    }
    __syncthreads();
#pragma unroll
    for (int p = 0; p < 4; ++p) {
        int r = r0 + p * 8;
        WbT[(size_t)(nt * 32 + r) * K_DIM + kt * 32 + c] = f2b(tile[c][r]);
    }
}

// ---------------------------------------------------------------------------
// Kernel 2: feat fp32 -> Xb[:, :512] bf16, fused dst-histogram.
// ---------------------------------------------------------------------------
__global__ __launch_bounds__(256) void convert_hist_kernel(const float* __restrict__ feat,
                                                           const int* __restrict__ dst,
                                                           unsigned short* __restrict__ Xb,
                                                           int* __restrict__ cnt) {
    const int gid = blockIdx.x * 256 + threadIdx.x;
    const int row = gid >> 6;
    const int l   = gid & 63;
    const float4* s = (const float4*)(feat + (size_t)row * D_IN + l * 8);
    float4 v0 = s[0], v1 = s[1];
    us8 o;
    o[0] = f2b(v0.x); o[1] = f2b(v0.y); o[2] = f2b(v0.z); o[3] = f2b(v0.w);
    o[4] = f2b(v1.x); o[5] = f2b(v1.y); o[6] = f2b(v1.z); o[7] = f2b(v1.w);
    *(us8*)(Xb + (size_t)row * K_DIM + l * 8) = o;
    if (gid < N_EDGES) atomicAdd(&cnt[dst[gid]], 1);
}

// ---------------------------------------------------------------------------
// Kernel 3: exclusive scan cnt[10000] -> rowstart[10001], cursor = rowstart
// ---------------------------------------------------------------------------
__global__ __launch_bounds__(256) void scan_kernel(const int* __restrict__ cnt,
                                                   int* __restrict__ rowstart,
                                                   int* __restrict__ cursor) {
    __shared__ int sums[256];
    const int t = threadIdx.x;
    const int base = t * 40;
    int s = 0;
#pragma unroll 8
    for (int i = 0; i < 40; ++i) {
        int idx = base + i;
        s += (idx < N_NODES) ? cnt[idx] : 0;
    }
    sums[t] = s;
    __syncthreads();
    for (int off = 1; off < 256; off <<= 1) {
        int v = (t >= off) ? sums[t - off] : 0;
        __syncthreads();
        sums[t] += v;
        __syncthreads();
    }
    int run = (t == 0) ? 0 : sums[t - 1];
    for (int i = 0; i < 40; ++i) {
        int idx = base + i;
        if (idx < N_NODES) {
            rowstart[idx] = run;
            cursor[idx]   = run;
            run += cnt[idx];
        }
    }
    if (t == 255) rowstart[N_NODES] = sums[255];
}

// ---------------------------------------------------------------------------
// Kernel 4: bucket fill.  eidx[cursor[d]++] = src[e]
// ---------------------------------------------------------------------------
__global__ __launch_bounds__(256) void bucket_kernel(const int* __restrict__ src,
                                                     const int* __restrict__ dst,
                                                     int* __restrict__ cursor,
                                                     int* __restrict__ eidx) {
    int e = blockIdx.x * 256 + threadIdx.x;
    int d = dst[e];
    int slot = atomicAdd(&cursor[d], 1);
    eidx[slot] = src[e];
}

// ---------------------------------------------------------------------------
// Kernel 5: gather-mean (bf16 in, bf16 out).  One wave per node.
//   Xb[node][512:1024] = (1/max(deg,1)) * sum_j Xb[eidx[j]][0:512]
// ---------------------------------------------------------------------------
__global__ __launch_bounds__(256) void gather_kernel(unsigned short* Xb,
                                                     const int* __restrict__ eidx,
                                                     const int* __restrict__ rowstart) {
    const int wv   = threadIdx.x >> 6;
    const int l    = threadIdx.x & 63;
    const int node = blockIdx.x * 4 + wv;
    const int beg  = rowstart[node];
    const int end  = rowstart[node + 1];
    float acc[8] = {0.f, 0.f, 0.f, 0.f, 0.f, 0.f, 0.f, 0.f};
    int j = beg;
    for (; j + 2 <= end; j += 2) {
        int s0 = eidx[j], s1 = eidx[j + 1];
        us8 v0 = *(const us8*)(Xb + (size_t)s0 * K_DIM + l * 8);
        us8 v1 = *(const us8*)(Xb + (size_t)s1 * K_DIM + l * 8);
#pragma unroll
        for (int i = 0; i < 8; ++i) { acc[i] += b2f(v0[i]); acc[i] += b2f(v1[i]); }
    }
    if (j < end) {
        int s0 = eidx[j];
        us8 v0 = *(const us8*)(Xb + (size_t)s0 * K_DIM + l * 8);
#pragma unroll
        for (int i = 0; i < 8; ++i) acc[i] += b2f(v0[i]);
    }
    float sc = 1.0f / fmaxf((float)(end - beg), 1.0f);
    us8 o;
#pragma unroll
    for (int i = 0; i < 8; ++i) o[i] = f2b(acc[i] * sc);
    *(us8*)(Xb + (size_t)node * K_DIM + D_IN + l * 8) = o;
}

// ---------------------------------------------------------------------------
// Kernel 6: GEMM  out[10000][512] = relu( Xb[10000][1024] @ WbT^T + b )
// 64x64 tile, BK=64, 4 waves (2x2), 32x32/wave, mfma_f32_16x16x32_bf16.
// Double-buffered LDS via global_load_lds(16B); XOR-swizzle (row&7)<<4 applied
// to the global SOURCE address (linear LDS dest) and to the ds_read address.
// ---------------------------------------------------------------------------
__global__ __launch_bounds__(256, 5) void gemm_kernel(const unsigned short* __restrict__ Xb,
                                                      const unsigned short* __restrict__ WbT,
                                                      const float* __restrict__ bias,
                                                      float* __restrict__ out) {
    __shared__ __align__(16) unsigned short As[2][4096];   // [64 rows][64 k] bf16
    __shared__ __align__(16) unsigned short Bs[2][4096];   // [64 cols][64 k] bf16

    const int tid = threadIdx.x;
    const int l   = tid & 63;
    const int w   = tid >> 6;
    const int wr  = w >> 1, wc = w & 1;
    const int brow = blockIdx.x * 64;
    const int bcol = blockIdx.y * 64;

    const int sub  = l >> 3;
    const int scol = ((l & 7) * 16) ^ (sub * 16);
    int ra0 = brow + w * 8 + sub;      ra0 = ra0 < N_NODES ? ra0 : N_NODES - 1;
    int ra1 = brow + 32 + w * 8 + sub; ra1 = ra1 < N_NODES ? ra1 : N_NODES - 1;
    const char* pa0 = (const char*)Xb  + (size_t)ra0 * 2048 + scol;
    const char* pa1 = (const char*)Xb  + (size_t)ra1 * 2048 + scol;
    const char* pb0 = (const char*)WbT + (size_t)(bcol + w * 8 + sub) * 2048 + scol;
    const char* pb1 = pb0 + 32 * 2048;

#define STAGE(buf, koff) do {                              \
        gl_lds16(pa0 + (koff), &As[buf][w * 512]);         \
        gl_lds16(pa1 + (koff), &As[buf][2048 + w * 512]);  \
        gl_lds16(pb0 + (koff), &Bs[buf][w * 512]);         \
        gl_lds16(pb1 + (koff), &Bs[buf][2048 + w * 512]);  \
    } while (0)

    const int fr = l & 15;
    const int g  = l >> 4;
    const int sw = (fr & 7) * 16;
    const int h0 = (((g * 16)     ) ^ sw) >> 1;
    const int h1 = (((64 + g * 16)) ^ sw) >> 1;
    const int rA = (wr * 32 + fr) * 64;
    const int rB = (wc * 32 + fr) * 64;

    f32x4 acc[2][2] = {};

    STAGE(0, 0);
    __syncthreads();
    int cur = 0;
#pragma unroll
    for (int t = 0; t < 16; ++t) {
        if (t < 15) STAGE(cur ^ 1, (t + 1) * 128);
        bf16x8 a00 = *(const bf16x8*)&As[cur][rA + h0];
        bf16x8 a01 = *(const bf16x8*)&As[cur][rA + h1];
        bf16x8 a10 = *(const bf16x8*)&As[cur][rA + 1024 + h0];
        bf16x8 a11 = *(const bf16x8*)&As[cur][rA + 1024 + h1];
        bf16x8 b00 = *(const bf16x8*)&Bs[cur][rB + h0];
        bf16x8 b01 = *(const bf16x8*)&Bs[cur][rB + h1];
        bf16x8 b10 = *(const bf16x8*)&Bs[cur][rB + 1024 + h0];
        bf16x8 b11 = *(const bf16x8*)&Bs[cur][rB + 1024 + h1];
        acc[0][0] = __builtin_amdgcn_mfma_f32_16x16x32_bf16(a00, b00, acc[0][0], 0, 0, 0);
        acc[0][0] = __builtin_amdgcn_mfma_f32_16x16x32_bf16(a01, b01, acc[0][0], 0, 0, 0);
        acc[0][1] = __builtin_amdgcn_mfma_f32_16x16x32_bf16(a00, b10, acc[0][1], 0, 0, 0);
        acc[0][1] = __builtin_amdgcn_mfma_f32_16x16x32_bf16(a01, b11, acc[0][1], 0, 0, 0);
        acc[1][0] = __builtin_amdgcn_mfma_f32_16x16x32_bf16(a10, b00, acc[1][0], 0, 0, 0);
        acc[1][0] = __builtin_amdgcn_mfma_f32_16x16x32_bf16(a11, b01, acc[1][0], 0, 0, 0);
        acc[1][1] = __builtin_amdgcn_mfma_f32_16x16x32_bf16(a10, b10, acc[1][1], 0, 0, 0);
        acc[1][1] = __builtin_amdgcn_mfma_f32_16x16x32_bf16(a11, b11, acc[1][1], 0, 0, 0);
        __syncthreads();
        cur ^= 1;
    }
#undef STAGE

#pragma unroll
    for (int n = 0; n < 2; ++n) {
        int col = bcol + wc * 32 + n * 16 + fr;
        float bv = bias[col];
#pragma unroll
        for (int m = 0; m < 2; ++m) {
            int row0 = brow + wr * 32 + m * 16 + g * 4;
#pragma unroll
            for (int j = 0; j < 4; ++j) {
                int row = row0 + j;
                if (row < N_NODES)
                    out[(size_t)row * D_OUT + col] = fmaxf(acc[m][n][j] + bv, 0.0f);
            }
        }
    }
}

// ---------------------------------------------------------------------------
// Launch.  ws layout (bytes):
//   [0,          20480000)  Xb        bf16 [10000][1024] (left=feat, right=mean)
//   [20480000,   20520000)  cnt       int  [10000]
//   [20520000,   20560016)  rowstart  int  [10001] (padded)
//   [20560016,   20600032)  cursor    int  [10001] (padded)
//   [20600032,   21240032)  eidx      int  [160000]
//   [21240032,   22288608)  WbT       bf16 [512][1024]
// ---------------------------------------------------------------------------
extern "C" void kernel_launch(void* const* d_in, const int* in_sizes, int n_in,
                              void* d_out, int out_size, void* d_ws, size_t ws_size,
                              hipStream_t stream) {
    const float* feat = (const float*)d_in[0];
    const int*   src  = (const int*)d_in[1];
    const int*   dst  = (const int*)d_in[2];
    const float* W    = (const float*)d_in[3];
    const float* bias = (const float*)d_in[4];
    float*       out  = (float*)d_out;

    char* ws = (char*)d_ws;
    unsigned short* Xb  = (unsigned short*)(ws);
    int*   cnt          = (int*)(ws + 20480000);
    int*   rowstart     = (int*)(ws + 20520000);
    int*   cursor       = (int*)(ws + 20560016);
    int*   eidx         = (int*)(ws + 20600032);
    unsigned short* WbT = (unsigned short*)(ws + 21240032);

    wtrans_kernel<<<dim3(32, 16), 256, 0, stream>>>(W, WbT, cnt);   // zeroes cnt
    convert_hist_kernel<<<2500, 256, 0, stream>>>(feat, dst, Xb, cnt);
    scan_kernel<<<1, 256, 0, stream>>>(cnt, rowstart, cursor);
    bucket_kernel<<<N_EDGES / 256, 256, 0, stream>>>(src, dst, cursor, eidx);
    gather_kernel<<<2500, 256, 0, stream>>>(Xb, eidx, rowstart);
    gemm_kernel<<<dim3(157, 8), 256, 0, stream>>>(Xb, WbT, bias, out);
}

// Round 5
// 108.998 us; speedup vs baseline: 10.6153x; 1.0862x over previous
//
#include <hip/hip_runtime.h>
#include <hip/hip_bf16.h>

// ---------------------------------------------------------------------------
// SAGEConv: out = relu(concat(feature, mean_{src->dst}(feature)) @ W + b)
// N=10000 nodes, E=160000 edges, D_IN=512, D_OUT=512, K=1024
// Round 5: GEMM BN 64->128 (halves A re-reads, 2x MFMA per barrier);
// gather unroll-4 for MLP.
// ---------------------------------------------------------------------------

#define N_NODES 10000
#define N_EDGES 160000
#define D_IN    512
#define D_OUT   512
#define K_DIM   1024

typedef float  f32x4  __attribute__((ext_vector_type(4)));
typedef __bf16 bf16x8 __attribute__((ext_vector_type(8)));
typedef unsigned short us8 __attribute__((ext_vector_type(8)));

__device__ __forceinline__ unsigned short f2b(float f) {
    unsigned int u = __float_as_uint(f);
    unsigned int r = u + 0x7FFFu + ((u >> 16) & 1u);   // round-to-nearest-even
    return (unsigned short)(r >> 16);
}
__device__ __forceinline__ float b2f(unsigned short h) {
    return __uint_as_float(((unsigned int)h) << 16);
}
// global -> LDS direct 16B load. LDS dest is wave-uniform base + lane*16;
// global src is per-lane.
__device__ __forceinline__ void gl_lds16(const void* g, void* l) {
    auto gp = (const __attribute__((address_space(1))) unsigned int*)(uintptr_t)g;
    auto lp = (__attribute__((address_space(3))) unsigned int*)(uintptr_t)l;
    __builtin_amdgcn_global_load_lds(gp, lp, 16, 0, 0);
}

// ---------------------------------------------------------------------------
// Kernel 1 (runs FIRST): W [1024][512] fp32 -> WbT [512][1024] bf16,
// fused cnt-zeroing (512 blocks x 20 ints = 10240 >= 10000).
// ---------------------------------------------------------------------------
__global__ __launch_bounds__(256) void wtrans_kernel(const float* __restrict__ W,
                                                     unsigned short* __restrict__ WbT,
                                                     int* __restrict__ cnt) {
    const int kt = blockIdx.x;   // 0..31
    const int nt = blockIdx.y;   // 0..15
    const int t  = threadIdx.x;

    const int bid = nt * 32 + kt;
    const int zi  = bid * 20 + t;
    if (t < 20 && zi < N_NODES) cnt[zi] = 0;

    __shared__ float tile[32][33];
    const int c  = t & 31;
    const int r0 = t >> 5;
#pragma unroll
    for (int p = 0; p < 4; ++p) {
        int r = r0 + p * 8;
        tile[r][c] = W[(size_t)(kt * 32 + r) * D_OUT + nt * 32 + c];
    }
    __syncthreads();
#pragma unroll
    for (int p = 0; p < 4; ++p) {
        int r = r0 + p * 8;
        WbT[(size_t)(nt * 32 + r) * K_DIM + kt * 32 + c] = f2b(tile[c][r]);
    }
}

// ---------------------------------------------------------------------------
// Kernel 2: feat fp32 -> Xb[:, :512] bf16, fused dst-histogram.
// ---------------------------------------------------------------------------
__global__ __launch_bounds__(256) void convert_hist_kernel(const float* __restrict__ feat,
                                                           const int* __restrict__ dst,
                                                           unsigned short* __restrict__ Xb,
                                                           int* __restrict__ cnt) {
    const int gid = blockIdx.x * 256 + threadIdx.x;
    const int row = gid >> 6;
    const int l   = gid & 63;
    const float4* s = (const float4*)(feat + (size_t)row * D_IN + l * 8);
    float4 v0 = s[0], v1 = s[1];
    us8 o;
    o[0] = f2b(v0.x); o[1] = f2b(v0.y); o[2] = f2b(v0.z); o[3] = f2b(v0.w);
    o[4] = f2b(v1.x); o[5] = f2b(v1.y); o[6] = f2b(v1.z); o[7] = f2b(v1.w);
    *(us8*)(Xb + (size_t)row * K_DIM + l * 8) = o;
    if (gid < N_EDGES) atomicAdd(&cnt[dst[gid]], 1);
}

// ---------------------------------------------------------------------------
// Kernel 3: exclusive scan cnt[10000] -> rowstart[10001], cursor = rowstart
// ---------------------------------------------------------------------------
__global__ __launch_bounds__(256) void scan_kernel(const int* __restrict__ cnt,
                                                   int* __restrict__ rowstart,
                                                   int* __restrict__ cursor) {
    __shared__ int sums[256];
    const int t = threadIdx.x;
    const int base = t * 40;
    int s = 0;
#pragma unroll 8
    for (int i = 0; i < 40; ++i) {
        int idx = base + i;
        s += (idx < N_NODES) ? cnt[idx] : 0;
    }
    sums[t] = s;
    __syncthreads();
    for (int off = 1; off < 256; off <<= 1) {
        int v = (t >= off) ? sums[t - off] : 0;
        __syncthreads();
        sums[t] += v;
        __syncthreads();
    }
    int run = (t == 0) ? 0 : sums[t - 1];
    for (int i = 0; i < 40; ++i) {
        int idx = base + i;
        if (idx < N_NODES) {
            rowstart[idx] = run;
            cursor[idx]   = run;
            run += cnt[idx];
        }
    }
    if (t == 255) rowstart[N_NODES] = sums[255];
}

// ---------------------------------------------------------------------------
// Kernel 4: bucket fill.  eidx[cursor[d]++] = src[e]
// ---------------------------------------------------------------------------
__global__ __launch_bounds__(256) void bucket_kernel(const int* __restrict__ src,
                                                     const int* __restrict__ dst,
                                                     int* __restrict__ cursor,
                                                     int* __restrict__ eidx) {
    int e = blockIdx.x * 256 + threadIdx.x;
    int d = dst[e];
    int slot = atomicAdd(&cursor[d], 1);
    eidx[slot] = src[e];
}

// ---------------------------------------------------------------------------
// Kernel 5: gather-mean (bf16 in, bf16 out).  One wave per node, unroll-4.
//   Xb[node][512:1024] = (1/max(deg,1)) * sum_j Xb[eidx[j]][0:512]
// ---------------------------------------------------------------------------
__global__ __launch_bounds__(256) void gather_kernel(unsigned short* Xb,
                                                     const int* __restrict__ eidx,
                                                     const int* __restrict__ rowstart) {
    const int wv   = threadIdx.x >> 6;
    const int l    = threadIdx.x & 63;
    const int node = blockIdx.x * 4 + wv;
    const int beg  = rowstart[node];
    const int end  = rowstart[node + 1];
    float acc[8] = {0.f, 0.f, 0.f, 0.f, 0.f, 0.f, 0.f, 0.f};
    int j = beg;
    for (; j + 4 <= end; j += 4) {
        int s0 = eidx[j], s1 = eidx[j + 1], s2 = eidx[j + 2], s3 = eidx[j + 3];
        us8 v0 = *(const us8*)(Xb + (size_t)s0 * K_DIM + l * 8);
        us8 v1 = *(const us8*)(Xb + (size_t)s1 * K_DIM + l * 8);
        us8 v2 = *(const us8*)(Xb + (size_t)s2 * K_DIM + l * 8);
        us8 v3 = *(const us8*)(Xb + (size_t)s3 * K_DIM + l * 8);
#pragma unroll
        for (int i = 0; i < 8; ++i)
            acc[i] += (b2f(v0[i]) + b2f(v1[i])) + (b2f(v2[i]) + b2f(v3[i]));
    }
    for (; j < end; ++j) {
        int s0 = eidx[j];
        us8 v0 = *(const us8*)(Xb + (size_t)s0 * K_DIM + l * 8);
#pragma unroll
        for (int i = 0; i < 8; ++i) acc[i] += b2f(v0[i]);
    }
    float sc = 1.0f / fmaxf((float)(end - beg), 1.0f);
    us8 o;
#pragma unroll
    for (int i = 0; i < 8; ++i) o[i] = f2b(acc[i] * sc);
    *(us8*)(Xb + (size_t)node * K_DIM + D_IN + l * 8) = o;
}

// ---------------------------------------------------------------------------
// Kernel 6: GEMM  out[10000][512] = relu( Xb[10000][1024] @ WbT^T + b )
// 64x128 tile (BMxBN), BK=64, 4 waves (2x2), 32x64/wave, mfma 16x16x32 bf16.
// Double-buffered LDS via global_load_lds(16B); XOR-swizzle (row&7)<<4 applied
// to the global SOURCE address (linear LDS dest) and to the ds_read address.
// Grid (157, 4) = 628 blocks; LDS 48KB -> 3 blocks/CU, all co-resident.
// ---------------------------------------------------------------------------
__global__ __launch_bounds__(256, 3) void gemm_kernel(const unsigned short* __restrict__ Xb,
                                                      const unsigned short* __restrict__ WbT,
                                                      const float* __restrict__ bias,
                                                      float* __restrict__ out) {
    __shared__ __align__(16) unsigned short As[2][4096];   // [64 rows][64 k] bf16
    __shared__ __align__(16) unsigned short Bs[2][8192];   // [128 cols][64 k] bf16

    const int tid = threadIdx.x;
    const int l   = tid & 63;
    const int w   = tid >> 6;
    const int wr  = w >> 1, wc = w & 1;
    const int brow = blockIdx.x * 64;
    const int bcol = blockIdx.y * 128;

    // staging: lane l covers row sub = l>>3 (row&7 == sub), 16B chunk (l&7)
    const int sub  = l >> 3;
    const int scol = ((l & 7) * 16) ^ (sub * 16);   // inverse swizzle on source
    int ra0 = brow + w * 8 + sub;      ra0 = ra0 < N_NODES ? ra0 : N_NODES - 1;
    int ra1 = brow + 32 + w * 8 + sub; ra1 = ra1 < N_NODES ? ra1 : N_NODES - 1;
    const char* pa0 = (const char*)Xb  + (size_t)ra0 * 2048 + scol;
    const char* pa1 = (const char*)Xb  + (size_t)ra1 * 2048 + scol;
    const char* pb0 = (const char*)WbT + (size_t)(bcol + w * 8 + sub) * 2048 + scol;
    const char* pb1 = pb0 + 32 * 2048;
    const char* pb2 = pb0 + 64 * 2048;
    const char* pb3 = pb0 + 96 * 2048;

#define STAGE(buf, koff) do {                              \
        gl_lds16(pa0 + (koff), &As[buf][w * 512]);         \
        gl_lds16(pa1 + (koff), &As[buf][2048 + w * 512]);  \
        gl_lds16(pb0 + (koff), &Bs[buf][w * 512]);         \
        gl_lds16(pb1 + (koff), &Bs[buf][2048 + w * 512]);  \
        gl_lds16(pb2 + (koff), &Bs[buf][4096 + w * 512]);  \
        gl_lds16(pb3 + (koff), &Bs[buf][6144 + w * 512]);  \
    } while (0)

    // fragment read addresses (swizzled)
    const int fr = l & 15;
    const int g  = l >> 4;
    const int sw = (fr & 7) * 16;
    const int h0 = (((g * 16)     ) ^ sw) >> 1;   // k-half 0, in shorts
    const int h1 = (((64 + g * 16)) ^ sw) >> 1;   // k-half 1
    const int rA = (wr * 32 + fr) * 64;
    int rB[4];
#pragma unroll
    for (int n = 0; n < 4; ++n) rB[n] = (wc * 64 + n * 16 + fr) * 64;

    f32x4 acc[2][4] = {};

    STAGE(0, 0);
    __syncthreads();
    int cur = 0;
#pragma unroll
    for (int t = 0; t < 16; ++t) {
        if (t < 15) STAGE(cur ^ 1, (t + 1) * 128);
        bf16x8 a00 = *(const bf16x8*)&As[cur][rA + h0];
        bf16x8 a01 = *(const bf16x8*)&As[cur][rA + h1];
        bf16x8 a10 = *(const bf16x8*)&As[cur][rA + 1024 + h0];
        bf16x8 a11 = *(const bf16x8*)&As[cur][rA + 1024 + h1];
#pragma unroll
        for (int n = 0; n < 4; ++n) {
            bf16x8 b0 = *(const bf16x8*)&Bs[cur][rB[n] + h0];
            bf16x8 b1 = *(const bf16x8*)&Bs[cur][rB[n] + h1];
            acc[0][n] = __builtin_amdgcn_mfma_f32_16x16x32_bf16(a00, b0, acc[0][n], 0, 0, 0);
            acc[0][n] = __builtin_amdgcn_mfma_f32_16x16x32_bf16(a01, b1, acc[0][n], 0, 0, 0);
            acc[1][n] = __builtin_amdgcn_mfma_f32_16x16x32_bf16(a10, b0, acc[1][n], 0, 0, 0);
            acc[1][n] = __builtin_amdgcn_mfma_f32_16x16x32_bf16(a11, b1, acc[1][n], 0, 0, 0);
        }
        __syncthreads();
        cur ^= 1;
    }
#undef STAGE

    // epilogue: bias + relu
#pragma unroll
    for (int n = 0; n < 4; ++n) {
        int col = bcol + wc * 64 + n * 16 + fr;
        float bv = bias[col];
#pragma unroll
        for (int m = 0; m < 2; ++m) {
            int row0 = brow + wr * 32 + m * 16 + g * 4;
#pragma unroll
            for (int j = 0; j < 4; ++j) {
                int row = row0 + j;
                if (row < N_NODES)
                    out[(size_t)row * D_OUT + col] = fmaxf(acc[m][n][j] + bv, 0.0f);
            }
        }
    }
}

// ---------------------------------------------------------------------------
// Launch.  ws layout (bytes):
//   [0,          20480000)  Xb        bf16 [10000][1024] (left=feat, right=mean)
//   [20480000,   20520000)  cnt       int  [10000]
//   [20520000,   20560016)  rowstart  int  [10001] (padded)
//   [20560016,   20600032)  cursor    int  [10001] (padded)
//   [20600032,   21240032)  eidx      int  [160000]
//   [21240032,   22288608)  WbT       bf16 [512][1024]
// ---------------------------------------------------------------------------
extern "C" void kernel_launch(void* const* d_in, const int* in_sizes, int n_in,
                              void* d_out, int out_size, void* d_ws, size_t ws_size,
                              hipStream_t stream) {
    const float* feat = (const float*)d_in[0];
    const int*   src  = (const int*)d_in[1];
    const int*   dst  = (const int*)d_in[2];
    const float* W    = (const float*)d_in[3];
    const float* bias = (const float*)d_in[4];
    float*       out  = (float*)d_out;

    char* ws = (char*)d_ws;
    unsigned short* Xb  = (unsigned short*)(ws);
    int*   cnt          = (int*)(ws + 20480000);
    int*   rowstart     = (int*)(ws + 20520000);
    int*   cursor       = (int*)(ws + 20560016);
    int*   eidx         = (int*)(ws + 20600032);
    unsigned short* WbT = (unsigned short*)(ws + 21240032);

    wtrans_kernel<<<dim3(32, 16), 256, 0, stream>>>(W, WbT, cnt);   // zeroes cnt
    convert_hist_kernel<<<2500, 256, 0, stream>>>(feat, dst, Xb, cnt);
    scan_kernel<<<1, 256, 0, stream>>>(cnt, rowstart, cursor);
    bucket_kernel<<<N_EDGES / 256, 256, 0, stream>>>(src, dst, cursor, eidx);
    gather_kernel<<<2500, 256, 0, stream>>>(Xb, eidx, rowstart);
    gemm_kernel<<<dim3(157, 4), 256, 0, stream>>>(Xb, WbT, bias, out);
}

// Round 6
// 91.534 us; speedup vs baseline: 12.6406x; 1.1908x over previous
//
#include <hip/hip_runtime.h>
#include <hip/hip_bf16.h>

// ---------------------------------------------------------------------------
// SAGEConv: out = relu(concat(feature, mean_{src->dst}(feature)) @ W + b)
// N=10000 nodes, E=160000 edges, D_IN=512, D_OUT=512, K=1024
// Round 6: GEMM 128x128 (64x64 wave-tile: 32 FLOP/LDS-byte, 2 blocks/CU,
// 316 blocks all co-resident); gather 2 waves/node for 2x MLP; int4 scan.
// ---------------------------------------------------------------------------

#define N_NODES 10000
#define N_EDGES 160000
#define D_IN    512
#define D_OUT   512
#define K_DIM   1024

typedef float  f32x4  __attribute__((ext_vector_type(4)));
typedef __bf16 bf16x8 __attribute__((ext_vector_type(8)));
typedef unsigned short us8 __attribute__((ext_vector_type(8)));
typedef unsigned short us4 __attribute__((ext_vector_type(4)));

__device__ __forceinline__ unsigned short f2b(float f) {
    unsigned int u = __float_as_uint(f);
    unsigned int r = u + 0x7FFFu + ((u >> 16) & 1u);   // round-to-nearest-even
    return (unsigned short)(r >> 16);
}
__device__ __forceinline__ float b2f(unsigned short h) {
    return __uint_as_float(((unsigned int)h) << 16);
}
// global -> LDS direct 16B load. LDS dest is wave-uniform base + lane*16;
// global src is per-lane.
__device__ __forceinline__ void gl_lds16(const void* g, void* l) {
    auto gp = (const __attribute__((address_space(1))) unsigned int*)(uintptr_t)g;
    auto lp = (__attribute__((address_space(3))) unsigned int*)(uintptr_t)l;
    __builtin_amdgcn_global_load_lds(gp, lp, 16, 0, 0);
}

// ---------------------------------------------------------------------------
// Kernel 1 (runs FIRST): W [1024][512] fp32 -> WbT [512][1024] bf16,
// fused cnt-zeroing (512 blocks x 20 ints = 10240 >= 10000).
// ---------------------------------------------------------------------------
__global__ __launch_bounds__(256) void wtrans_kernel(const float* __restrict__ W,
                                                     unsigned short* __restrict__ WbT,
                                                     int* __restrict__ cnt) {
    const int kt = blockIdx.x;   // 0..31
    const int nt = blockIdx.y;   // 0..15
    const int t  = threadIdx.x;

    const int bid = nt * 32 + kt;
    const int zi  = bid * 20 + t;
    if (t < 20 && zi < N_NODES) cnt[zi] = 0;

    __shared__ float tile[32][33];
    const int c  = t & 31;
    const int r0 = t >> 5;
#pragma unroll
    for (int p = 0; p < 4; ++p) {
        int r = r0 + p * 8;
        tile[r][c] = W[(size_t)(kt * 32 + r) * D_OUT + nt * 32 + c];
    }
    __syncthreads();
#pragma unroll
    for (int p = 0; p < 4; ++p) {
        int r = r0 + p * 8;
        WbT[(size_t)(nt * 32 + r) * K_DIM + kt * 32 + c] = f2b(tile[c][r]);
    }
}

// ---------------------------------------------------------------------------
// Kernel 2: feat fp32 -> Xb[:, :512] bf16, fused dst-histogram.
// ---------------------------------------------------------------------------
__global__ __launch_bounds__(256) void convert_hist_kernel(const float* __restrict__ feat,
                                                           const int* __restrict__ dst,
                                                           unsigned short* __restrict__ Xb,
                                                           int* __restrict__ cnt) {
    const int gid = blockIdx.x * 256 + threadIdx.x;
    const int row = gid >> 6;
    const int l   = gid & 63;
    const float4* s = (const float4*)(feat + (size_t)row * D_IN + l * 8);
    float4 v0 = s[0], v1 = s[1];
    us8 o;
    o[0] = f2b(v0.x); o[1] = f2b(v0.y); o[2] = f2b(v0.z); o[3] = f2b(v0.w);
    o[4] = f2b(v1.x); o[5] = f2b(v1.y); o[6] = f2b(v1.z); o[7] = f2b(v1.w);
    *(us8*)(Xb + (size_t)row * K_DIM + l * 8) = o;
    if (gid < N_EDGES) atomicAdd(&cnt[dst[gid]], 1);
}

// ---------------------------------------------------------------------------
// Kernel 3: exclusive scan cnt[10000] -> rowstart[10001], cursor = rowstart
// int4-vectorized walks (40 elems/thread, 16B aligned).
// ---------------------------------------------------------------------------
__global__ __launch_bounds__(256) void scan_kernel(const int* __restrict__ cnt,
                                                   int* __restrict__ rowstart,
                                                   int* __restrict__ cursor) {
    __shared__ int sums[256];
    const int t = threadIdx.x;
    const int base = t * 40;
    const int4* c4 = (const int4*)(cnt + base);
    int s = 0;
    if (base < N_NODES) {
#pragma unroll
        for (int i = 0; i < 10; ++i) {
            int4 v = c4[i];
            s += v.x + v.y + v.z + v.w;
        }
    }
    sums[t] = s;
    __syncthreads();
    for (int off = 1; off < 256; off <<= 1) {
        int v = (t >= off) ? sums[t - off] : 0;
        __syncthreads();
        sums[t] += v;
        __syncthreads();
    }
    int run = (t == 0) ? 0 : sums[t - 1];
    if (base < N_NODES) {
        int4* r4 = (int4*)(rowstart + base);
        int4* u4 = (int4*)(cursor + base);
#pragma unroll
        for (int i = 0; i < 10; ++i) {
            int4 v = c4[i];
            int4 o;
            o.x = run;  o.y = run + v.x;  o.z = run + v.x + v.y;
            o.w = run + v.x + v.y + v.z;
            run += v.x + v.y + v.z + v.w;
            r4[i] = o;
            u4[i] = o;
        }
    }
    if (t == 255) rowstart[N_NODES] = sums[255];
}

// ---------------------------------------------------------------------------
// Kernel 4: bucket fill.  eidx[cursor[d]++] = src[e]
// ---------------------------------------------------------------------------
__global__ __launch_bounds__(256) void bucket_kernel(const int* __restrict__ src,
                                                     const int* __restrict__ dst,
                                                     int* __restrict__ cursor,
                                                     int* __restrict__ eidx) {
    int e = blockIdx.x * 256 + threadIdx.x;
    int d = dst[e];
    int slot = atomicAdd(&cursor[d], 1);
    eidx[slot] = src[e];
}

// ---------------------------------------------------------------------------
// Kernel 5: gather-mean (bf16 in, bf16 out).  TWO waves per node (256 cols
// each, 8B/lane) for 2x memory-level parallelism; unroll-4 over edges.
//   Xb[node][512:1024] = (1/max(deg,1)) * sum_j Xb[eidx[j]][0:512]
// ---------------------------------------------------------------------------
__global__ __launch_bounds__(256) void gather_kernel(unsigned short* Xb,
                                                     const int* __restrict__ eidx,
                                                     const int* __restrict__ rowstart) {
    const int wv   = threadIdx.x >> 6;
    const int l    = threadIdx.x & 63;
    const int node = blockIdx.x * 2 + (wv >> 1);
    const int half = wv & 1;
    const int col  = half * 256 + l * 4;            // shorts
    const int beg  = rowstart[node];
    const int end  = rowstart[node + 1];
    float a0 = 0.f, a1 = 0.f, a2 = 0.f, a3 = 0.f;
    int j = beg;
    for (; j + 4 <= end; j += 4) {
        int s0 = eidx[j], s1 = eidx[j + 1], s2 = eidx[j + 2], s3 = eidx[j + 3];
        us4 v0 = *(const us4*)(Xb + (size_t)s0 * K_DIM + col);
        us4 v1 = *(const us4*)(Xb + (size_t)s1 * K_DIM + col);
        us4 v2 = *(const us4*)(Xb + (size_t)s2 * K_DIM + col);
        us4 v3 = *(const us4*)(Xb + (size_t)s3 * K_DIM + col);
        a0 += (b2f(v0[0]) + b2f(v1[0])) + (b2f(v2[0]) + b2f(v3[0]));
        a1 += (b2f(v0[1]) + b2f(v1[1])) + (b2f(v2[1]) + b2f(v3[1]));
        a2 += (b2f(v0[2]) + b2f(v1[2])) + (b2f(v2[2]) + b2f(v3[2]));
        a3 += (b2f(v0[3]) + b2f(v1[3])) + (b2f(v2[3]) + b2f(v3[3]));
    }
    for (; j < end; ++j) {
        int s0 = eidx[j];
        us4 v0 = *(const us4*)(Xb + (size_t)s0 * K_DIM + col);
        a0 += b2f(v0[0]); a1 += b2f(v0[1]); a2 += b2f(v0[2]); a3 += b2f(v0[3]);
    }
    float sc = 1.0f / fmaxf((float)(end - beg), 1.0f);
    us4 o;
    o[0] = f2b(a0 * sc); o[1] = f2b(a1 * sc); o[2] = f2b(a2 * sc); o[3] = f2b(a3 * sc);
    *(us4*)(Xb + (size_t)node * K_DIM + D_IN + col) = o;
}

// ---------------------------------------------------------------------------
// Kernel 6: GEMM  out[10000][512] = relu( Xb[10000][1024] @ WbT^T + b )
// 128x128 tile, BK=64, 4 waves (2x2), 64x64 wave-tile, mfma 16x16x32 bf16.
// 16 ds_read_b128 : 32 MFMA per wave-K-step (32 FLOP/LDS-byte).
// Double-buffered LDS via global_load_lds(16B); XOR-swizzle (row&7)<<4 on the
// global SOURCE address (linear LDS dest) and on the ds_read address.
// Grid (79, 4) = 316 blocks; LDS 64KB -> 2 blocks/CU, all co-resident.
// ---------------------------------------------------------------------------
__global__ __launch_bounds__(256, 2) void gemm_kernel(const unsigned short* __restrict__ Xb,
                                                      const unsigned short* __restrict__ WbT,
                                                      const float* __restrict__ bias,
                                                      float* __restrict__ out) {
    __shared__ __align__(16) unsigned short As[2][8192];   // [128 rows][64 k] bf16
    __shared__ __align__(16) unsigned short Bs[2][8192];   // [128 cols][64 k] bf16

    const int tid = threadIdx.x;
    const int l   = tid & 63;
    const int w   = tid >> 6;
    const int wr  = w >> 1, wc = w & 1;
    const int brow = blockIdx.x * 128;
    const int bcol = blockIdx.y * 128;

    // staging: lane l covers row sub = l>>3 (row&7 == sub), 16B chunk (l&7)
    const int sub  = l >> 3;
    const int scol = ((l & 7) * 16) ^ (sub * 16);   // inverse swizzle on source
    const char* pa[4];
    const char* pb[4];
#pragma unroll
    for (int p = 0; p < 4; ++p) {
        int ra = brow + p * 32 + w * 8 + sub;
        ra = ra < N_NODES ? ra : N_NODES - 1;
        pa[p] = (const char*)Xb + (size_t)ra * 2048 + scol;
        pb[p] = (const char*)WbT + (size_t)(bcol + p * 32 + w * 8 + sub) * 2048 + scol;
    }

#define STAGE(buf, koff) do {                                          \
        gl_lds16(pa[0] + (koff), &As[buf][(0 * 32 + w * 8) * 64]);     \
        gl_lds16(pa[1] + (koff), &As[buf][(1 * 32 + w * 8) * 64]);     \
        gl_lds16(pa[2] + (koff), &As[buf][(2 * 32 + w * 8) * 64]);     \
        gl_lds16(pa[3] + (koff), &As[buf][(3 * 32 + w * 8) * 64]);     \
        gl_lds16(pb[0] + (koff), &Bs[buf][(0 * 32 + w * 8) * 64]);     \
        gl_lds16(pb[1] + (koff), &Bs[buf][(1 * 32 + w * 8) * 64]);     \
        gl_lds16(pb[2] + (koff), &Bs[buf][(2 * 32 + w * 8) * 64]);     \
        gl_lds16(pb[3] + (koff), &Bs[buf][(3 * 32 + w * 8) * 64]);     \
    } while (0)

    // fragment read addresses (swizzled): row*64 shorts + ((kh*64+g*16)^sw)/2
    const int fr = l & 15;
    const int g  = l >> 4;
    const int sw = (fr & 7) * 16;
    const int h0 = ((g * 16)       ^ sw) >> 1;   // kh=0, in shorts
    const int h1 = ((64 + g * 16)  ^ sw) >> 1;   // kh=1

    f32x4 acc[4][4] = {};

    STAGE(0, 0);
    __syncthreads();
    int cur = 0;
#pragma unroll 2
    for (int t = 0; t < 16; ++t) {
        if (t < 15) STAGE(cur ^ 1, (t + 1) * 128);
        bf16x8 a[4][2], b[4][2];
#pragma unroll
        for (int m = 0; m < 4; ++m) {
            int r = (wr * 64 + m * 16 + fr) * 64;
            a[m][0] = *(const bf16x8*)&As[cur][r + h0];
            a[m][1] = *(const bf16x8*)&As[cur][r + h1];
        }
#pragma unroll
        for (int n = 0; n < 4; ++n) {
            int r = (wc * 64 + n * 16 + fr) * 64;
            b[n][0] = *(const bf16x8*)&Bs[cur][r + h0];
            b[n][1] = *(const bf16x8*)&Bs[cur][r + h1];
        }
#pragma unroll
        for (int kh = 0; kh < 2; ++kh)
#pragma unroll
            for (int m = 0; m < 4; ++m)
#pragma unroll
                for (int n = 0; n < 4; ++n)
                    acc[m][n] = __builtin_amdgcn_mfma_f32_16x16x32_bf16(a[m][kh], b[n][kh], acc[m][n], 0, 0, 0);
        __syncthreads();
        cur ^= 1;
    }
#undef STAGE

    // epilogue: bias + relu
#pragma unroll
    for (int n = 0; n < 4; ++n) {
        int col = bcol + wc * 64 + n * 16 + fr;
        float bv = bias[col];
#pragma unroll
        for (int m = 0; m < 4; ++m) {
            int row0 = brow + wr * 64 + m * 16 + g * 4;
#pragma unroll
            for (int j = 0; j < 4; ++j) {
                int row = row0 + j;
                if (row < N_NODES)
                    out[(size_t)row * D_OUT + col] = fmaxf(acc[m][n][j] + bv, 0.0f);
            }
        }
    }
}

// ---------------------------------------------------------------------------
// Launch.  ws layout (bytes):
//   [0,          20480000)  Xb        bf16 [10000][1024] (left=feat, right=mean)
//   [20480000,   20520000)  cnt       int  [10000]
//   [20520000,   20560016)  rowstart  int  [10001] (padded)
//   [20560016,   20600032)  cursor    int  [10001] (padded)
//   [20600032,   21240032)  eidx      int  [160000]
//   [21240032,   22288608)  WbT       bf16 [512][1024]
// ---------------------------------------------------------------------------
extern "C" void kernel_launch(void* const* d_in, const int* in_sizes, int n_in,
                              void* d_out, int out_size, void* d_ws, size_t ws_size,
                              hipStream_t stream) {
    const float* feat = (const float*)d_in[0];
    const int*   src  = (const int*)d_in[1];
    const int*   dst  = (const int*)d_in[2];
    const float* W    = (const float*)d_in[3];
    const float* bias = (const float*)d_in[4];
    float*       out  = (float*)d_out;

    char* ws = (char*)d_ws;
    unsigned short* Xb  = (unsigned short*)(ws);
    int*   cnt          = (int*)(ws + 20480000);
    int*   rowstart     = (int*)(ws + 20520000);
    int*   cursor       = (int*)(ws + 20560016);
    int*   eidx         = (int*)(ws + 20600032);
    unsigned short* WbT = (unsigned short*)(ws + 21240032);

    wtrans_kernel<<<dim3(32, 16), 256, 0, stream>>>(W, WbT, cnt);   // zeroes cnt
    convert_hist_kernel<<<2500, 256, 0, stream>>>(feat, dst, Xb, cnt);
    scan_kernel<<<1, 256, 0, stream>>>(cnt, rowstart, cursor);
    bucket_kernel<<<N_EDGES / 256, 256, 0, stream>>>(src, dst, cursor, eidx);
    gather_kernel<<<5000, 256, 0, stream>>>(Xb, eidx, rowstart);
    gemm_kernel<<<dim3(79, 4), 256, 0, stream>>>(Xb, WbT, bias, out);
}